// Round 1
// baseline (718.157 us; speedup 1.0000x reference)
//
#include <hip/hip_runtime.h>
#include <hip/hip_bf16.h>

#define D 400
#define DPAD 416
#define LC 2048
#define LA 512
#define BM 128
#define BN 128
#define BK 32
#define ITERS 13   // ceil(400/32) with zero-padded tail

typedef __attribute__((ext_vector_type(8))) short bf16x8;
typedef __attribute__((ext_vector_type(4))) float f32x4;

static __device__ __forceinline__ unsigned pk2(float x, float y) {
    __hip_bfloat162 h = __float22bfloat162_rn(make_float2(x, y));
    union { __hip_bfloat162 h; unsigned u; } c; c.h = h; return c.u;
}

__global__ __launch_bounds__(256)
void align_kernel(const float* __restrict__ ctx, const float* __restrict__ asp,
                  const float* __restrict__ w_u, float* __restrict__ out) {
    __shared__ short As[BM * BK];
    __shared__ short Bs[BN * BK];
    __shared__ float w1s[DPAD], w2s[DPAD], w3s[DPAD];
    __shared__ float tAs[BM], tBs[BN];

    const int tid = threadIdx.x;

    // XCD-aware swizzle: the 4 nb-blocks sharing one ctx A-block land on the
    // same XCD (indices 8 apart -> same blockIdx%8 bucket).
    int L = blockIdx.x;
    int u = L & 7, v = L >> 3;
    int nb = v & 3;
    int g = ((v >> 2) << 3) | u;   // 0..1023 = (b, mb)
    int b = g >> 4, mb = g & 15;

    for (int i = tid; i < DPAD; i += 256) {
        w1s[i] = (i < D) ? w_u[i] : 0.f;
        w2s[i] = (i < D) ? w_u[D + i] : 0.f;
        w3s[i] = (i < D) ? w_u[2 * D + i] : 0.f;
    }
    __syncthreads();

    const int rg = tid >> 3;   // 0..31 : staging row group
    const int cg = tid & 7;    // 0..7  : staging col group (4 floats each)
    const float* ctxb = ctx + ((size_t)b * LC + (size_t)mb * BM) * D;
    const float* aspb = asp + ((size_t)b * LA + (size_t)nb * BN) * D;

    const int lane = tid & 63;
    const int wave = tid >> 6;
    const int wm = (wave >> 1) * 64;   // wave row offset in tile
    const int wn = (wave & 1) * 64;    // wave col offset in tile
    const int lr = lane & 15;
    const int lk = (lane >> 4) * 8;

    f32x4 acc[4][4];
    #pragma unroll
    for (int i = 0; i < 4; i++)
        #pragma unroll
        for (int j = 0; j < 4; j++)
            acc[i][j] = (f32x4){0.f, 0.f, 0.f, 0.f};

    float tA[4] = {0.f, 0.f, 0.f, 0.f};
    float tB[4] = {0.f, 0.f, 0.f, 0.f};

    for (int it = 0; it < ITERS; it++) {
        const int k0 = it * BK;
        const int col = k0 + cg * 4;
        const bool valid = (col < D);   // float4 is all-valid or all-pad (400%4==0)
        const float4 w1v = *(const float4*)&w1s[col];
        const float4 w2v = *(const float4*)&w2s[col];
        const float4 w3v = *(const float4*)&w3s[col];

        #pragma unroll
        for (int p = 0; p < 4; p++) {
            const int row = rg + p * 32;

            float4 x = make_float4(0.f, 0.f, 0.f, 0.f);
            if (valid) x = *(const float4*)&ctxb[(size_t)row * D + col];
            tA[p] += x.x * w1v.x + x.y * w1v.y + x.z * w1v.z + x.w * w1v.w;
            unsigned alo = pk2(x.x * w3v.x, x.y * w3v.y);
            unsigned ahi = pk2(x.z * w3v.z, x.w * w3v.w);
            *(uint2*)&As[row * BK + cg * 4] = make_uint2(alo, ahi);

            float4 y = make_float4(0.f, 0.f, 0.f, 0.f);
            if (valid) y = *(const float4*)&aspb[(size_t)row * D + col];
            tB[p] += y.x * w2v.x + y.y * w2v.y + y.z * w2v.z + y.w * w2v.w;
            unsigned blo = pk2(y.x, y.y);
            unsigned bhi = pk2(y.z, y.w);
            *(uint2*)&Bs[row * BK + cg * 4] = make_uint2(blo, bhi);
        }
        __syncthreads();

        bf16x8 af[4], bfr[4];
        #pragma unroll
        for (int mi = 0; mi < 4; mi++)
            af[mi] = *(const bf16x8*)&As[(wm + mi * 16 + lr) * BK + lk];
        #pragma unroll
        for (int ni = 0; ni < 4; ni++)
            bfr[ni] = *(const bf16x8*)&Bs[(wn + ni * 16 + lr) * BK + lk];
        #pragma unroll
        for (int mi = 0; mi < 4; mi++)
            #pragma unroll
            for (int ni = 0; ni < 4; ni++)
                acc[mi][ni] = __builtin_amdgcn_mfma_f32_16x16x32_bf16(
                    af[mi], bfr[ni], acc[mi][ni], 0, 0, 0);
        __syncthreads();
    }

    // Reduce fp32 term partials across the 8 lanes of each cg-group
    // (lanes 8m..8m+7 are xor-closed under 1,2,4).
    #pragma unroll
    for (int p = 0; p < 4; p++) {
        float s = tA[p];
        s += __shfl_xor(s, 1); s += __shfl_xor(s, 2); s += __shfl_xor(s, 4);
        if (cg == 0) tAs[rg + p * 32] = s;
        float t = tB[p];
        t += __shfl_xor(t, 1); t += __shfl_xor(t, 2); t += __shfl_xor(t, 4);
        if (cg == 0) tBs[rg + p * 32] = t;
    }
    __syncthreads();

    float* outb = out + ((size_t)b * LC + (size_t)mb * BM) * LA + (size_t)nb * BN;
    #pragma unroll
    for (int mi = 0; mi < 4; mi++) {
        #pragma unroll
        for (int ni = 0; ni < 4; ni++) {
            const int c = wn + ni * 16 + lr;
            const float tb = tBs[c];
            #pragma unroll
            for (int r = 0; r < 4; r++) {
                const int rr = wm + mi * 16 + (lane >> 4) * 4 + r;
                outb[(size_t)rr * LA + c] = acc[mi][ni][r] + tAs[rr] + tb;
            }
        }
    }
}

extern "C" void kernel_launch(void* const* d_in, const int* in_sizes, int n_in,
                              void* d_out, int out_size, void* d_ws, size_t ws_size,
                              hipStream_t stream) {
    // setup_inputs order: batch_size (int scalar), ctx, asp, w_u — all fp32
    const float* ctx = (const float*)d_in[1];
    const float* asp = (const float*)d_in[2];
    const float* w_u = (const float*)d_in[3];
    float* out = (float*)d_out;
    hipLaunchKernelGGL(align_kernel, dim3(64 * 16 * 4), dim3(256), 0, stream,
                       ctx, asp, w_u, out);
}

// Round 2
// 561.731 us; speedup vs baseline: 1.2785x; 1.2785x over previous
//
#include <hip/hip_runtime.h>
#include <hip/hip_bf16.h>

#define D 400
#define DP 448           // K padded to 7*64, zeros in pad
#define LC 2048
#define LA 512
#define NBATCH 64
#define BM 128
#define BN 128
#define BK 64
#define KIT 7

typedef __attribute__((ext_vector_type(8))) short bf16x8;
typedef __attribute__((ext_vector_type(4))) float f32x4;

static __device__ __forceinline__ unsigned pk2(float x, float y) {
    __hip_bfloat162 h = __float22bfloat162_rn(make_float2(x, y));
    union { __hip_bfloat162 h; unsigned u; } c; c.h = h; return c.u;
}

static __device__ __forceinline__ void gl2lds16(const unsigned short* g, unsigned short* l) {
    __builtin_amdgcn_global_load_lds(
        (const __attribute__((address_space(1))) unsigned int*)g,
        (__attribute__((address_space(3))) unsigned int*)l, 16, 0, 0);
}

// ---------------- Pass 1: convert (+optional w3-scale) + term dot ----------------
// 8 rows per 256-thread block, 32 lanes per row. Reads fp32 row [D], writes bf16 row [DP].
template <bool SCALE>
__global__ __launch_bounds__(256)
void prep_kernel(const float* __restrict__ src, const float* __restrict__ wdot,
                 const float* __restrict__ wscale,
                 unsigned short* __restrict__ dst, float* __restrict__ term) {
    const int r = blockIdx.x * 8 + (threadIdx.x >> 5);
    const int c = threadIdx.x & 31;
    const float4* s4 = (const float4*)(src + (size_t)r * D);
    uint2* d2 = (uint2*)(dst + (size_t)r * DP);
    float part = 0.f;
    #pragma unroll
    for (int idx = 0; idx < DP / 4; idx += 32) {
        const int i = idx + c;
        if (i >= DP / 4) break;
        uint2 o = make_uint2(0u, 0u);
        if (i < D / 4) {
            float4 x = ((const float4*)src)[0], w;
            x = s4[i];
            w = ((const float4*)wdot)[i];
            part += x.x * w.x + x.y * w.y + x.z * w.z + x.w * w.w;
            if (SCALE) {
                float4 s = ((const float4*)wscale)[i];
                x.x *= s.x; x.y *= s.y; x.z *= s.z; x.w *= s.w;
            }
            o.x = pk2(x.x, x.y);
            o.y = pk2(x.z, x.w);
        }
        d2[i] = o;
    }
    part += __shfl_xor(part, 1); part += __shfl_xor(part, 2);
    part += __shfl_xor(part, 4); part += __shfl_xor(part, 8);
    part += __shfl_xor(part, 16);
    if (c == 0) term[r] = part;
}

// ---------------- Pass 2: bf16 GEMM via global_load_lds, swizzled LDS ----------------
__global__ __launch_bounds__(256)
void gemm_kernel(const unsigned short* __restrict__ A, const unsigned short* __restrict__ B,
                 const float* __restrict__ termA, const float* __restrict__ termB,
                 float* __restrict__ out) {
    __shared__ unsigned short As[BM * BK];
    __shared__ unsigned short Bs[BN * BK];
    __shared__ float tAs[BM], tBs[BN];

    // XCD swizzle: 4 nb-blocks sharing one A-block land in same blockIdx%8 bucket
    const int L = blockIdx.x;
    const int u = L & 7, v = L >> 3;
    const int nb = v & 3;
    const int g = ((v >> 2) << 3) | u;
    const int b = g >> 4, mb = g & 15;

    const int tid = threadIdx.x;
    const int lane = tid & 63, wave = tid >> 6;

    if (tid < BM) tAs[tid] = termA[(size_t)b * LC + mb * BM + tid];
    else if (tid < BM + BN) tBs[tid - BM] = termB[(size_t)b * LA + nb * BN + (tid - BM)];

    const unsigned short* Ab = A + ((size_t)b * LC + (size_t)mb * BM) * DP;
    const unsigned short* Bb = B + ((size_t)b * LA + (size_t)nb * BN) * DP;

    // staging: instr j covers 8 rows (lane>>3), 8 chunks of 16B (lane&7) per row.
    // LDS[row][pos] = global[row][pos ^ (row&7)]  (row&7 == lane>>3 here)
    const int srow = wave * 32 + (lane >> 3);
    const int schunk = (lane & 7) ^ (lane >> 3);

    const int wm = (wave >> 1) * 64, wn = (wave & 1) * 64;
    const int lr = lane & 15, quad = lane >> 4;

    f32x4 acc[4][4];
    #pragma unroll
    for (int i = 0; i < 4; i++)
        #pragma unroll
        for (int j = 0; j < 4; j++)
            acc[i][j] = (f32x4){0.f, 0.f, 0.f, 0.f};

    for (int it = 0; it < KIT; it++) {
        const int kof = it * BK;
        #pragma unroll
        for (int j = 0; j < 4; j++) {
            gl2lds16(Ab + (size_t)(srow + j * 8) * DP + kof + schunk * 8,
                     &As[(wave * 32 + j * 8) * BK]);
            gl2lds16(Bb + (size_t)(srow + j * 8) * DP + kof + schunk * 8,
                     &Bs[(wave * 32 + j * 8) * BK]);
        }
        __syncthreads();   // compiler drains vmcnt(0) before s_barrier

        #pragma unroll
        for (int ks = 0; ks < 2; ks++) {
            bf16x8 af[4], bfr[4];
            const int pos = (ks * 4 + quad) ^ (lr & 7);   // row&7 == lr&7
            #pragma unroll
            for (int mi = 0; mi < 4; mi++)
                af[mi] = *(const bf16x8*)&As[(wm + mi * 16 + lr) * BK + pos * 8];
            #pragma unroll
            for (int ni = 0; ni < 4; ni++)
                bfr[ni] = *(const bf16x8*)&Bs[(wn + ni * 16 + lr) * BK + pos * 8];
            #pragma unroll
            for (int mi = 0; mi < 4; mi++)
                #pragma unroll
                for (int ni = 0; ni < 4; ni++)
                    acc[mi][ni] = __builtin_amdgcn_mfma_f32_16x16x32_bf16(
                        af[mi], bfr[ni], acc[mi][ni], 0, 0, 0);
        }
        __syncthreads();
    }

    float* outb = out + ((size_t)b * LC + (size_t)mb * BM) * LA + (size_t)nb * BN;
    #pragma unroll
    for (int mi = 0; mi < 4; mi++) {
        #pragma unroll
        for (int ni = 0; ni < 4; ni++) {
            const int c = wn + ni * 16 + lr;
            const float tb = tBs[c];
            #pragma unroll
            for (int r = 0; r < 4; r++) {
                const int rr = wm + mi * 16 + quad * 4 + r;
                outb[(size_t)rr * LA + c] = acc[mi][ni][r] + tAs[rr] + tb;
            }
        }
    }
}

// ---------------- Fallback (R1 fused kernel) if ws too small ----------------
#define FDPAD 416
#define FBK 32
#define FITERS 13
__global__ __launch_bounds__(256)
void align_kernel(const float* __restrict__ ctx, const float* __restrict__ asp,
                  const float* __restrict__ w_u, float* __restrict__ out) {
    __shared__ short As[BM * FBK];
    __shared__ short Bs[BN * FBK];
    __shared__ float w1s[FDPAD], w2s[FDPAD], w3s[FDPAD];
    __shared__ float tAs[BM], tBs[BN];
    const int tid = threadIdx.x;
    int L = blockIdx.x;
    int u = L & 7, v = L >> 3;
    int nb = v & 3;
    int g = ((v >> 2) << 3) | u;
    int b = g >> 4, mb = g & 15;
    for (int i = tid; i < FDPAD; i += 256) {
        w1s[i] = (i < D) ? w_u[i] : 0.f;
        w2s[i] = (i < D) ? w_u[D + i] : 0.f;
        w3s[i] = (i < D) ? w_u[2 * D + i] : 0.f;
    }
    __syncthreads();
    const int rg = tid >> 3;
    const int cg = tid & 7;
    const float* ctxb = ctx + ((size_t)b * LC + (size_t)mb * BM) * D;
    const float* aspb = asp + ((size_t)b * LA + (size_t)nb * BN) * D;
    const int lane = tid & 63;
    const int wave = tid >> 6;
    const int wm = (wave >> 1) * 64;
    const int wn = (wave & 1) * 64;
    const int lr = lane & 15;
    const int lk = (lane >> 4) * 8;
    f32x4 acc[4][4];
    #pragma unroll
    for (int i = 0; i < 4; i++)
        #pragma unroll
        for (int j = 0; j < 4; j++)
            acc[i][j] = (f32x4){0.f, 0.f, 0.f, 0.f};
    float tA[4] = {0.f, 0.f, 0.f, 0.f};
    float tB[4] = {0.f, 0.f, 0.f, 0.f};
    for (int it = 0; it < FITERS; it++) {
        const int col = it * FBK + cg * 4;
        const bool valid = (col < D);
        const float4 w1v = *(const float4*)&w1s[col];
        const float4 w2v = *(const float4*)&w2s[col];
        const float4 w3v = *(const float4*)&w3s[col];
        #pragma unroll
        for (int p = 0; p < 4; p++) {
            const int row = rg + p * 32;
            float4 x = make_float4(0.f, 0.f, 0.f, 0.f);
            if (valid) x = *(const float4*)&ctxb[(size_t)row * D + col];
            tA[p] += x.x * w1v.x + x.y * w1v.y + x.z * w1v.z + x.w * w1v.w;
            *(uint2*)&As[row * FBK + cg * 4] =
                make_uint2(pk2(x.x * w3v.x, x.y * w3v.y), pk2(x.z * w3v.z, x.w * w3v.w));
            float4 y = make_float4(0.f, 0.f, 0.f, 0.f);
            if (valid) y = *(const float4*)&aspb[(size_t)row * D + col];
            tB[p] += y.x * w2v.x + y.y * w2v.y + y.z * w2v.z + y.w * w2v.w;
            *(uint2*)&Bs[row * FBK + cg * 4] = make_uint2(pk2(y.x, y.y), pk2(y.z, y.w));
        }
        __syncthreads();
        bf16x8 af[4], bfr[4];
        #pragma unroll
        for (int mi = 0; mi < 4; mi++)
            af[mi] = *(const bf16x8*)&As[(wm + mi * 16 + lr) * FBK + lk];
        #pragma unroll
        for (int ni = 0; ni < 4; ni++)
            bfr[ni] = *(const bf16x8*)&Bs[(wn + ni * 16 + lr) * FBK + lk];
        #pragma unroll
        for (int mi = 0; mi < 4; mi++)
            #pragma unroll
            for (int ni = 0; ni < 4; ni++)
                acc[mi][ni] = __builtin_amdgcn_mfma_f32_16x16x32_bf16(
                    af[mi], bfr[ni], acc[mi][ni], 0, 0, 0);
        __syncthreads();
    }
    #pragma unroll
    for (int p = 0; p < 4; p++) {
        float s = tA[p];
        s += __shfl_xor(s, 1); s += __shfl_xor(s, 2); s += __shfl_xor(s, 4);
        if (cg == 0) tAs[rg + p * 32] = s;
        float t = tB[p];
        t += __shfl_xor(t, 1); t += __shfl_xor(t, 2); t += __shfl_xor(t, 4);
        if (cg == 0) tBs[rg + p * 32] = t;
    }
    __syncthreads();
    float* outb = out + ((size_t)b * LC + (size_t)mb * BM) * LA + (size_t)nb * BN;
    #pragma unroll
    for (int mi = 0; mi < 4; mi++) {
        #pragma unroll
        for (int ni = 0; ni < 4; ni++) {
            const int c = wn + ni * 16 + lr;
            const float tb = tBs[c];
            #pragma unroll
            for (int r = 0; r < 4; r++) {
                const int rr = wm + mi * 16 + (lane >> 4) * 4 + r;
                outb[(size_t)rr * LA + c] = acc[mi][ni][r] + tAs[rr] + tb;
            }
        }
    }
}

extern "C" void kernel_launch(void* const* d_in, const int* in_sizes, int n_in,
                              void* d_out, int out_size, void* d_ws, size_t ws_size,
                              hipStream_t stream) {
    const float* ctx = (const float*)d_in[1];
    const float* asp = (const float*)d_in[2];
    const float* w_u = (const float*)d_in[3];
    float* out = (float*)d_out;

    const size_t nrA = (size_t)NBATCH * LC;          // 131072
    const size_t nrB = (size_t)NBATCH * LA;          // 32768
    const size_t offA = 0;
    const size_t offB = offA + nrA * DP * 2;         // 117,440,512
    const size_t offTA = offB + nrB * DP * 2;        // 146,800,640
    const size_t offTB = offTA + nrA * 4;            // 147,324,928
    const size_t need = offTB + nrB * 4;             // 147,456,000

    if (ws_size >= need) {
        unsigned short* Aw = (unsigned short*)((char*)d_ws + offA);
        unsigned short* Bw = (unsigned short*)((char*)d_ws + offB);
        float* tA = (float*)((char*)d_ws + offTA);
        float* tB = (float*)((char*)d_ws + offTB);
        // ctx: pure convert + w1 dot
        hipLaunchKernelGGL((prep_kernel<false>), dim3(nrA / 8), dim3(256), 0, stream,
                           ctx, w_u, (const float*)nullptr, Aw, tA);
        // asp: scale by w3 + convert + w2 dot
        hipLaunchKernelGGL((prep_kernel<true>), dim3(nrB / 8), dim3(256), 0, stream,
                           asp, w_u + D, w_u + 2 * D, Bw, tB);
        hipLaunchKernelGGL(gemm_kernel, dim3(NBATCH * 16 * 4), dim3(256), 0, stream,
                           Aw, Bw, tA, tB, out);
    } else {
        hipLaunchKernelGGL(align_kernel, dim3(NBATCH * 16 * 4), dim3(256), 0, stream,
                           ctx, asp, w_u, out);
    }
}